// Round 3
// baseline (2749.773 us; speedup 1.0000x reference)
//
#include <hip/hip_runtime.h>
#include <math.h>

// ---- model constants ----
#define BS_TOT   1024          // B*S
#define DM       256           // d_model
#define DST      128           // d_state
#define TSTEPS   8
#define DECAYF   0.6065306597126334f
#define SCALEF   0.17677669529663689f   // 1/sqrt(32)
#define NE       (BS_TOT * DM)          // 262144

// ======================= embedding =======================
__global__ void embed_k(const int* __restrict__ ids, const float* __restrict__ emb,
                        float* __restrict__ tok) {
    int r = blockIdx.x, c = threadIdx.x;
    tok[r * DM + c] = emb[(size_t)ids[r] * DM + c];
}

// ======================= per-layer init / weight transpose =======================
// grid 1024 x 256 (covers 262144 threads)
__global__ void init_k(float* __restrict__ hb0, float* __restrict__ hb1,
                       float* __restrict__ svb0, float* __restrict__ svb1,
                       float* __restrict__ ovb0, float* __restrict__ ovb1,
                       float* __restrict__ W1T, float* __restrict__ B1,
                       float* __restrict__ WoT, float* __restrict__ CT,
                       const float* __restrict__ Al, const float* __restrict__ Wql,
                       const float* __restrict__ bql, const float* __restrict__ Wol,
                       const float* __restrict__ Cl, int* __restrict__ cnts) {
    int i = blockIdx.x * 256 + threadIdx.x;
    if (i < BS_TOT * DST) { hb0[i] = 0.f; hb1[i] = 0.f; svb0[i] = 0.f; svb1[i] = 0.f; }
    ovb0[i] = 0.f; ovb1[i] = 0.f;        // grid is exactly 262144
    if (i < 32768) {
        int k = i >> 8, n = i & 255;
        W1T[i] = (n < 128) ? Al[n * 128 + k] : Wql[(n - 128) * 128 + k];
        CT[i]  = Cl[n * 128 + k];
    }
    if (i < 16384) {
        int k = i >> 7, n = i & 127;
        WoT[i] = Wol[n * 128 + k];
    }
    if (i < 256) B1[i] = (i < 128) ? 0.f : bql[i - 128];
    if (i < 16) cnts[i] = 0;             // cnt1[8], cnt2[8]
}

// ======================= k-half transpose: kv[key][0..127] -> kT[d][key] ============
// grid (16 key-chunks, nt time-slices), 256 threads
__global__ __launch_bounds__(256) void ktrans_k(const float* __restrict__ kv,
                                                float* __restrict__ kT) {
    __shared__ float tile[64][133];
    const float* src = kv + (size_t)blockIdx.y * NE;
    float* dst = kT + (size_t)blockIdx.y * (128 * 1024);
    const int kc = blockIdx.x, tid = threadIdx.x;
#pragma unroll
    for (int i = 0; i < 32; ++i) {
        int idx = i * 256 + tid;
        int key = idx >> 7, d = idx & 127;
        tile[key][d] = src[(size_t)(kc * 64 + key) * 256 + d];
    }
    __syncthreads();
#pragma unroll
    for (int i = 0; i < 32; ++i) {
        int idx = i * 256 + tid;
        int d = idx >> 6, key = idx & 63;
        dst[(size_t)d * 1024 + kc * 64 + key] = tile[key][d];
    }
}

// ======================= time-mean =======================
__global__ void mean_k(const float* __restrict__ outs, float* __restrict__ ti) {
    int i = blockIdx.x * 256 + threadIdx.x;
    float s = 0.f;
#pragma unroll
    for (int t = 0; t < TSTEPS; ++t) s += outs[t * NE + i];
    ti[i] = s * 0.125f;
}

// ======================= generic fp32 GEMM (plain, +bias) =======================
// C[M,N] = A[M,K] @ W[N,K]^T (+bias). Ascending-k accumulation (bit-stable).
template <int BM, int BN, int BK, int TM, int TN>
__global__ __launch_bounds__((BM / TM) * (BN / TN))
void gemm_k(const float* __restrict__ Amat, const float* __restrict__ Wmat,
            const float* __restrict__ bias, float* __restrict__ outp,
            int M, int N, int K) {
    constexpr int NT  = (BM / TM) * (BN / TN);
    constexpr int NXT = BN / TN;
    __shared__ float As[BK][BM + 4];
    __shared__ float Bs[BK][BN + 4];
    const int tid = threadIdx.x;
    const int n0 = blockIdx.x * BN, m0 = blockIdx.y * BM;
    const int tx = tid % NXT, ty = tid / NXT;
    float acc[TM][TN] = {};

    for (int k0 = 0; k0 < K; k0 += BK) {
#pragma unroll
        for (int i = 0; i < (BM * BK) / NT; ++i) {
            int idx = i * NT + tid;
            int kk = idx % BK, mm = idx / BK;
            As[kk][mm] = Amat[(size_t)(m0 + mm) * K + k0 + kk];
        }
#pragma unroll
        for (int i = 0; i < (BN * BK) / NT; ++i) {
            int idx = i * NT + tid;
            int kk = idx % BK, nn = idx / BK;
            Bs[kk][nn] = Wmat[(size_t)(n0 + nn) * K + k0 + kk];
        }
        __syncthreads();
#pragma unroll
        for (int kk = 0; kk < BK; ++kk) {
            float a[TM], b[TN];
#pragma unroll
            for (int i = 0; i < TM; ++i) a[i] = As[kk][ty * TM + i];
#pragma unroll
            for (int j = 0; j < TN; ++j) b[j] = Bs[kk][tx * TN + j];
#pragma unroll
            for (int i = 0; i < TM; ++i)
#pragma unroll
                for (int j = 0; j < TN; ++j) acc[i][j] += a[i] * b[j];
        }
        __syncthreads();
    }
#pragma unroll
    for (int i = 0; i < TM; ++i) {
        int mr = m0 + ty * TM + i;
#pragma unroll
        for (int j = 0; j < TN; ++j) {
            int nc = n0 + tx * TN + j;
            float x = acc[i][j];
            if (bias) x += bias[nc];
            outp[(size_t)mr * N + nc] = x;
        }
    }
}

// ======================= fused phase-shifted SNN step =======================
// Kernel K_t: phase A = LIF-part of step t-1 (st + att@WoT + LIF1 -> h2 ; h2@CT
// + LIF2 -> outs[t-1]), duplicated across the 4 head-blocks of each row-tile
// (identical values; count atomics scaled x4). Phase B = q/scores/softmax/PV of
// step t for this block's head. grid = 128 row-tiles x 4 heads = 512 blocks.
__global__ __launch_bounds__(256) void fstep_k(
    const float* __restrict__ kT,          // [128][1024] k^T for this t
    const float* __restrict__ kv,          // [1024][256] (v half used)
    const float* __restrict__ W1T,         // [128][256]
    const float* __restrict__ B1,          // [256]
    const float* __restrict__ WoT,         // [128][128]
    const float* __restrict__ CT,          // [128][256]
    const float* __restrict__ bo,          // [128]
    const float* __restrict__ h_old,       // h(t-2)
    float* __restrict__ h_new,            // h(t-1) (out; holds zeros when t==0)
    const float* __restrict__ sv_in, float* __restrict__ sv_out,
    const float* __restrict__ ov_in, float* __restrict__ ov_out,
    const float* __restrict__ att_in,      // att(t-1)
    float* __restrict__ att_out,           // att(t)
    float* __restrict__ outs_prev,         // outs[t-1]
    int* __restrict__ cnt1, int* __restrict__ cnt2, int t, int do_B)
{
    __shared__ float p_s[8 * 1024];
    __shared__ float hA_s[8 * 128];
    __shared__ float h2_s[8 * 128];
    __shared__ float att_s[8 * 128];
    __shared__ float q_s[8 * 36];
    __shared__ float red_s[8 * 33];
    __shared__ float mrow_s[8], linv_s[8], thr_s[2];

    const int tid = threadIdx.x;
    const int hh = blockIdx.x >> 7;
    const int tile = blockIdx.x & 127;
    const int r0 = tile * 8;

    if (t > 0) {
        // ---- A0: thresholds (recomputed from x4-scaled counts) + loads ----
        if (tid == 0) {
            float ts = 1.0f, to = 1.0f;
            for (int i = 0; i < t - 1; ++i) {
                float e1 = (float)cnt1[i] * (1.f / 524288.f) - 0.02f;   // /(4*131072)
                ts = fmaxf(ts + 0.1f * e1, 0.5f);
                float e2 = (float)cnt2[i] * (1.f / 1048576.f) - 0.02f;  // /(4*262144)
                to = fmaxf(to + 0.1f * e2, 0.5f);
            }
            thr_s[0] = ts; thr_s[1] = to;
        }
#pragma unroll
        for (int i = 0; i < 4; ++i) {
            int idx = i * 256 + tid;
            hA_s[idx]  = h_old[r0 * 128 + idx];
            att_s[idx] = att_in[r0 * 128 + idx];
        }
        __syncthreads();

        // ---- A1: st = h_old@W1T[:128], b = att@WoT; upd -> LIF1 -> h2 ----
        {
            const int n = tid & 127, half = tid >> 7;
            float st[4] = {0.f, 0.f, 0.f, 0.f};
            float b[4]  = {0.f, 0.f, 0.f, 0.f};
            for (int k4 = 0; k4 < 32; ++k4) {
                const int k = k4 * 4;
                float w10 = W1T[(k + 0) * 256 + n];
                float w11 = W1T[(k + 1) * 256 + n];
                float w12 = W1T[(k + 2) * 256 + n];
                float w13 = W1T[(k + 3) * 256 + n];
                float wo0 = WoT[(k + 0) * 128 + n];
                float wo1 = WoT[(k + 1) * 128 + n];
                float wo2 = WoT[(k + 2) * 128 + n];
                float wo3 = WoT[(k + 3) * 128 + n];
#pragma unroll
                for (int r4 = 0; r4 < 4; ++r4) {
                    int r = half * 4 + r4;
                    float4 hv = *(const float4*)&hA_s[r * 128 + k];
                    float4 av = *(const float4*)&att_s[r * 128 + k];
                    st[r4] += hv.x * w10; st[r4] += hv.y * w11;
                    st[r4] += hv.z * w12; st[r4] += hv.w * w13;
                    b[r4] += av.x * wo0; b[r4] += av.y * wo1;
                    b[r4] += av.z * wo2; b[r4] += av.w * wo3;
                }
            }
            float ts = thr_s[0];
            int my1 = 0;
#pragma unroll
            for (int r4 = 0; r4 < 4; ++r4) {
                int r = half * 4 + r4, row = r0 + r;
                float stv = st[r4] + 0.0f;            // match round-1's st + B1(=0)
                float x = b[r4] + bo[n];
                x += stv;
                float v = sv_in[row * 128 + n];
                float vp = v * DECAYF + x;
                float sp = (vp - ts >= 0.f) ? 1.f : 0.f;
                h_new[row * 128 + n] = sp;
                h2_s[r * 128 + n] = sp;
                sv_out[row * 128 + n] = vp * (1.f - sp);
                my1 += (int)sp;
            }
#pragma unroll
            for (int off = 32; off > 0; off >>= 1) my1 += __shfl_down(my1, off, 64);
            if ((tid & 63) == 0) atomicAdd(&cnt1[t - 1], my1);
        }
        __syncthreads();

        // ---- A2: out_pot = h2@CT -> LIF2 -> outs[t-1] ----
        {
            const int n = tid;
            float acc[8] = {0.f, 0.f, 0.f, 0.f, 0.f, 0.f, 0.f, 0.f};
            for (int k4 = 0; k4 < 32; ++k4) {
                const int k = k4 * 4;
                float c0 = CT[(k + 0) * 256 + n];
                float c1 = CT[(k + 1) * 256 + n];
                float c2 = CT[(k + 2) * 256 + n];
                float c3 = CT[(k + 3) * 256 + n];
#pragma unroll
                for (int r = 0; r < 8; ++r) {
                    float4 hv = *(const float4*)&h2_s[r * 128 + k];
                    acc[r] += hv.x * c0; acc[r] += hv.y * c1;
                    acc[r] += hv.z * c2; acc[r] += hv.w * c3;
                }
            }
            float to = thr_s[1];
            int my2 = 0;
#pragma unroll
            for (int r = 0; r < 8; ++r) {
                int row = r0 + r;
                float vo = ov_in[row * 256 + n];
                float vp = vo * DECAYF + acc[r];
                float sp = (vp - to >= 0.f) ? 1.f : 0.f;
                outs_prev[(size_t)row * 256 + n] = sp;
                ov_out[row * 256 + n] = vp * (1.f - sp);
                my2 += (int)sp;
            }
#pragma unroll
            for (int off = 32; off > 0; off >>= 1) my2 += __shfl_down(my2, off, 64);
            if ((tid & 63) == 0) atomicAdd(&cnt2[t - 1], my2);
        }
        // h2_s already published by the barrier after A1; A2 doesn't touch it.
    } else {
        // t == 0: h(t-1) = zeros (h_new buffer was zero-initialized)
#pragma unroll
        for (int i = 0; i < 4; ++i) {
            int idx = i * 256 + tid;
            h2_s[idx] = h_new[r0 * 128 + idx];
        }
        __syncthreads();
    }

    if (!do_B) return;

    // ---- B1: q[r][d] for this head (dense ascending-k, matches reference) ----
    {
        const int r = tid >> 5, d = tid & 31;
        const int col = 128 + hh * 32 + d;
        float acc = 0.f;
        for (int k4 = 0; k4 < 32; ++k4) {
            const int k = k4 * 4;
            float4 hv = *(const float4*)&h2_s[r * 128 + k];
            float w0 = W1T[(k + 0) * 256 + col];
            float w1 = W1T[(k + 1) * 256 + col];
            float w2 = W1T[(k + 2) * 256 + col];
            float w3 = W1T[(k + 3) * 256 + col];
            acc += hv.x * w0; acc += hv.y * w1; acc += hv.z * w2; acc += hv.w * w3;
        }
        q_s[r * 36 + d] = acc + B1[col];
    }
    __syncthreads();

    // ---- B2: scores (coalesced kT loads; ascending-d chains) ----
    {
        const float* kTh = kT + hh * 32 * 1024;
        for (int c = 0; c < 4; ++c) {
            const int key = c * 256 + tid;
            float kreg[32];
#pragma unroll
            for (int d = 0; d < 32; ++d) kreg[d] = kTh[d * 1024 + key];
            float acc[8];
#pragma unroll
            for (int r = 0; r < 8; ++r) acc[r] = 0.f;
#pragma unroll
            for (int d4 = 0; d4 < 8; ++d4) {
#pragma unroll
                for (int r = 0; r < 8; ++r) {
                    float4 qv = *(const float4*)&q_s[r * 36 + d4 * 4];
                    acc[r] += qv.x * kreg[d4 * 4 + 0];
                    acc[r] += qv.y * kreg[d4 * 4 + 1];
                    acc[r] += qv.z * kreg[d4 * 4 + 2];
                    acc[r] += qv.w * kreg[d4 * 4 + 3];
                }
            }
#pragma unroll
            for (int r = 0; r < 8; ++r) p_s[r * 1024 + key] = acc[r] * SCALEF;
        }
    }
    __syncthreads();

    // ---- B3: softmax (identical reduction shapes to rounds 1/2) ----
    {
        const int rh = tid >> 5, lg = tid & 31;
        float mx = -1e30f;
        for (int jj = 0; jj < 32; ++jj) mx = fmaxf(mx, p_s[rh * 1024 + lg + 32 * jj]);
        red_s[rh * 33 + lg] = mx;
        __syncthreads();
        if (tid < 8) {
            float m = red_s[tid * 33];
            for (int j = 1; j < 32; ++j) m = fmaxf(m, red_s[tid * 33 + j]);
            mrow_s[tid] = m;
        }
        __syncthreads();
        float m = mrow_s[rh];
        float ls = 0.f;
        for (int jj = 0; jj < 32; ++jj) {
            int a = rh * 1024 + lg + 32 * jj;
            float p = expf(p_s[a] - m);
            p_s[a] = p;
            ls += p;
        }
        red_s[rh * 33 + lg] = ls;
        __syncthreads();
        if (tid < 8) {
            float l = 0.f;
            for (int j = 0; j < 32; ++j) l += red_s[tid * 33 + j];
            linv_s[tid] = 1.0f / l;
        }
    }
    __syncthreads();

    // ---- B4: PV (ascending key 0..1023 per output) ----
    {
        const int r = tid >> 5, d = tid & 31;
        const int col = 128 + hh * 32 + d;
        float acc = 0.f;
        for (int k4 = 0; k4 < 256; ++k4) {
            const int key = k4 * 4;
            float4 pv = *(const float4*)&p_s[r * 1024 + key];
            float v0 = kv[(key + 0) * 256 + col];
            float v1 = kv[(key + 1) * 256 + col];
            float v2 = kv[(key + 2) * 256 + col];
            float v3 = kv[(key + 3) * 256 + col];
            acc += pv.x * v0; acc += pv.y * v1; acc += pv.z * v2; acc += pv.w * v3;
        }
        att_out[(r0 + r) * 128 + hh * 32 + d] = acc * linv_s[r];
    }
}

// ======================= host =======================
extern "C" void kernel_launch(void* const* d_in, const int* in_sizes, int n_in,
                              void* d_out, int out_size, void* d_ws, size_t ws_size,
                              hipStream_t stream) {
    (void)in_sizes; (void)n_in; (void)out_size; (void)ws_size;
    const int*   ids  = (const int*)d_in[0];
    const float* emb  = (const float*)d_in[1];
    const float* Aw   = (const float*)d_in[2];
    const float* Cw   = (const float*)d_in[3];
    const float* Wq   = (const float*)d_in[4];
    const float* bq   = (const float*)d_in[5];
    const float* Wkv  = (const float*)d_in[6];
    const float* bkv  = (const float*)d_in[7];
    const float* Wo   = (const float*)d_in[8];
    const float* bo   = (const float*)d_in[9];
    const float* Wout = (const float*)d_in[10];
    const float* bout = (const float*)d_in[11];
    float* out = (float*)d_out;
    float* ws  = (float*)d_ws;

    float* tok  = ws;                       // 262144
    float* bufA = tok  + NE;                // 8*262144
    float* bufB = bufA + 8 * NE;            // 8*262144
    float* kvb  = bufB + 8 * NE;            // 8*262144
    float* kTb  = kvb  + 8 * NE;            // 8*131072
    float* attb0 = kTb  + 8 * 131072;       // 131072
    float* attb1 = attb0 + 131072;          // 131072
    float* hb0  = attb1 + 131072;           // 131072
    float* hb1  = hb0  + 131072;            // 131072
    float* svb0 = hb1  + 131072;            // 131072
    float* svb1 = svb0 + 131072;            // 131072
    float* ovb0 = svb1 + 131072;            // 262144
    float* ovb1 = ovb0 + 262144;            // 262144
    float* ti   = ovb1 + 262144;            // 262144
    float* W1T  = ti   + NE;                // 32768
    float* B1   = W1T  + 32768;             // 256
    float* WoT  = B1   + 256;               // 16384
    float* CT   = WoT  + 16384;             // 32768
    int*   cnts = (int*)(CT + 32768);       // cnt1[8], cnt2[8]

    float* hb[2]   = {hb0, hb1};
    float* svb[2]  = {svb0, svb1};
    float* ovb[2]  = {ovb0, ovb1};
    float* attb[2] = {attb0, attb1};

    embed_k<<<dim3(1024), dim3(256), 0, stream>>>(ids, emb, tok);

    for (int l = 0; l < 2; ++l) {
        const float* Al   = Aw  + l * 16384;
        const float* Cl   = Cw  + l * 32768;
        const float* Wql  = Wq  + l * 16384;
        const float* bql  = bq  + l * 128;
        const float* Wkvl = Wkv + l * 65536;
        const float* bkvl = bkv + l * 256;
        const float* Wol  = Wo  + l * 16384;
        const float* bol  = bo  + l * 128;
        const float* xin  = (l == 0) ? tok : bufA;
        float* outs       = (l == 0) ? bufA : bufB;
        const int Mkv     = (l == 0) ? BS_TOT : 8 * BS_TOT;
        const int nt      = (l == 0) ? 1 : 8;

        init_k<<<dim3(1024), dim3(256), 0, stream>>>(hb0, hb1, svb0, svb1, ovb0, ovb1,
                                                     W1T, B1, WoT, CT,
                                                     Al, Wql, bql, Wol, Cl, cnts);

        // kv for the whole layer (ascending-k order identical to rounds 1/2)
        gemm_k<64, 64, 16, 4, 4><<<dim3(256 / 64, Mkv / 64), dim3(256), 0, stream>>>(
            xin, Wkvl, bkvl, kvb, Mkv, 256, 256);

        ktrans_k<<<dim3(16, nt), dim3(256), 0, stream>>>(kvb, kTb);

        for (int t = 0; t <= TSTEPS; ++t) {
            const int do_B = (t < TSTEPS) ? 1 : 0;
            const int tt = (t < TSTEPS) ? t : (TSTEPS - 1);   // kv/kT index clamp (unused when !do_B)
            const float* kT_t = (l == 0) ? kTb : kTb + (size_t)tt * 131072;
            const float* kv_t = (l == 0) ? kvb : kvb + (size_t)tt * NE;
            float* outs_prev = outs + (size_t)((t > 0) ? (t - 1) : 0) * NE;
            const int grid = do_B ? 512 : 128;
            fstep_k<<<dim3(grid), dim3(256), 0, stream>>>(
                kT_t, kv_t, W1T, B1, WoT, CT, bol,
                hb[t & 1], hb[(t + 1) & 1],
                svb[t & 1], svb[(t + 1) & 1],
                ovb[t & 1], ovb[(t + 1) & 1],
                attb[(t + 1) & 1], attb[t & 1],
                outs_prev, cnts, cnts + 8, t, do_B);
        }
    }

    mean_k<<<dim3(1024), dim3(256), 0, stream>>>(bufB, ti);

    // logits = ti @ Wout^T + bout  (round-1 measured config: 216 us)
    gemm_k<64, 64, 16, 4, 4><<<dim3(32000 / 64, BS_TOT / 64), dim3(256), 0, stream>>>(
        ti, Wout, bout, out, BS_TOT, 32000, 256);
}

// Round 4
// 1287.526 us; speedup vs baseline: 2.1357x; 2.1357x over previous
//
#include <hip/hip_runtime.h>
#include <math.h>

// ---- model constants ----
#define BS_TOT   1024          // B*S
#define DM       256           // d_model
#define DST      128           // d_state
#define TSTEPS   8
#define DECAYF   0.6065306597126334f
#define SCALEF   0.17677669529663689f   // 1/sqrt(32)
#define NE       (BS_TOT * DM)          // 262144

// ======================= embedding =======================
__global__ void embed_k(const int* __restrict__ ids, const float* __restrict__ emb,
                        float* __restrict__ tok) {
    int r = blockIdx.x, c = threadIdx.x;
    tok[r * DM + c] = emb[(size_t)ids[r] * DM + c];
}

// ======================= per-layer init / weight transpose =======================
__global__ void init_k(float* __restrict__ hb0, float* __restrict__ hb1,
                       float* __restrict__ svb0, float* __restrict__ svb1,
                       float* __restrict__ ovb0, float* __restrict__ ovb1,
                       float* __restrict__ W1T, float* __restrict__ B1,
                       float* __restrict__ WoT, float* __restrict__ CT,
                       const float* __restrict__ Al, const float* __restrict__ Wql,
                       const float* __restrict__ bql, const float* __restrict__ Wol,
                       const float* __restrict__ Cl, int* __restrict__ cnts) {
    int i = blockIdx.x * 256 + threadIdx.x;
    if (i < BS_TOT * DST) { hb0[i] = 0.f; hb1[i] = 0.f; svb0[i] = 0.f; svb1[i] = 0.f; }
    ovb0[i] = 0.f; ovb1[i] = 0.f;        // grid is exactly 262144
    if (i < 32768) {
        int k = i >> 8, n = i & 255;
        W1T[i] = (n < 128) ? Al[n * 128 + k] : Wql[(n - 128) * 128 + k];
        CT[i]  = Cl[n * 128 + k];
    }
    if (i < 16384) {
        int k = i >> 7, n = i & 127;
        WoT[i] = Wol[n * 128 + k];
    }
    if (i < 256) B1[i] = (i < 128) ? 0.f : bql[i - 128];
    if (i < 16) cnts[i] = 0;             // cnt1[8], cnt2[8]
}

// ======================= k-half transpose: kv[key][0..127] -> kT[d][key] ============
__global__ __launch_bounds__(256) void ktrans_k(const float* __restrict__ kv,
                                                float* __restrict__ kT) {
    __shared__ float tile[64][133];
    const float* src = kv + (size_t)blockIdx.y * NE;
    float* dst = kT + (size_t)blockIdx.y * (128 * 1024);
    const int kc = blockIdx.x, tid = threadIdx.x;
#pragma unroll
    for (int i = 0; i < 32; ++i) {
        int idx = i * 256 + tid;
        int key = idx >> 7, d = idx & 127;
        tile[key][d] = src[(size_t)(kc * 64 + key) * 256 + d];
    }
    __syncthreads();
#pragma unroll
    for (int i = 0; i < 32; ++i) {
        int idx = i * 256 + tid;
        int d = idx >> 6, key = idx & 63;
        dst[(size_t)d * 1024 + kc * 64 + key] = tile[key][d];
    }
}

// ======================= time-mean =======================
__global__ void mean_k(const float* __restrict__ outs, float* __restrict__ ti) {
    int i = blockIdx.x * 256 + threadIdx.x;
    float s = 0.f;
#pragma unroll
    for (int t = 0; t < TSTEPS; ++t) s += outs[t * NE + i];
    ti[i] = s * 0.125f;
}

// ======================= generic fp32 GEMM (plain, +bias) =======================
// C[M,N] = A[M,K] @ W[N,K]^T (+bias). Ascending-k fma accumulation (bit-stable).
template <int BM, int BN, int BK, int TM, int TN>
__global__ __launch_bounds__((BM / TM) * (BN / TN))
void gemm_k(const float* __restrict__ Amat, const float* __restrict__ Wmat,
            const float* __restrict__ bias, float* __restrict__ outp,
            int M, int N, int K) {
    constexpr int NT  = (BM / TM) * (BN / TN);
    constexpr int NXT = BN / TN;
    __shared__ float As[BK][BM + 4];
    __shared__ float Bs[BK][BN + 4];
    const int tid = threadIdx.x;
    const int n0 = blockIdx.x * BN, m0 = blockIdx.y * BM;
    const int tx = tid % NXT, ty = tid / NXT;
    float acc[TM][TN] = {};

    for (int k0 = 0; k0 < K; k0 += BK) {
#pragma unroll
        for (int i = 0; i < (BM * BK) / NT; ++i) {
            int idx = i * NT + tid;
            int kk = idx % BK, mm = idx / BK;
            As[kk][mm] = Amat[(size_t)(m0 + mm) * K + k0 + kk];
        }
#pragma unroll
        for (int i = 0; i < (BN * BK) / NT; ++i) {
            int idx = i * NT + tid;
            int kk = idx % BK, nn = idx / BK;
            Bs[kk][nn] = Wmat[(size_t)(n0 + nn) * K + k0 + kk];
        }
        __syncthreads();
#pragma unroll
        for (int kk = 0; kk < BK; ++kk) {
            float a[TM], b[TN];
#pragma unroll
            for (int i = 0; i < TM; ++i) a[i] = As[kk][ty * TM + i];
#pragma unroll
            for (int j = 0; j < TN; ++j) b[j] = Bs[kk][tx * TN + j];
#pragma unroll
            for (int i = 0; i < TM; ++i)
#pragma unroll
                for (int j = 0; j < TN; ++j) acc[i][j] += a[i] * b[j];
        }
        __syncthreads();
    }
#pragma unroll
    for (int i = 0; i < TM; ++i) {
        int mr = m0 + ty * TM + i;
#pragma unroll
        for (int j = 0; j < TN; ++j) {
            int nc = n0 + tx * TN + j;
            float x = acc[i][j];
            if (bias) x += bias[nc];
            outp[(size_t)mr * N + nc] = x;
        }
    }
}

// ======================= fused phase-shifted SNN step =======================
// Kernel K_t: phase A = LIF of step t-1 (st + att@WoT + LIF1 -> h2; h2@CT + LIF2),
// computed by all head-blocks (h2 needed locally) but written/counted only by
// hh==0 blocks. Phase B = q/scores/softmax/PV of step t for this block's head.
// grid = 128 row-tiles x 4 heads = 512 blocks, 256 threads (8 rows per block).
__global__ __launch_bounds__(256) void fstep_k(
    const float* __restrict__ kT,          // [128][1024] k^T for this t
    const float* __restrict__ kv,          // [1024][256] (v half used)
    const float* __restrict__ W1T,         // [128][256]
    const float* __restrict__ B1,          // [256]
    const float* __restrict__ WoT,         // [128][128]
    const float* __restrict__ CT,          // [128][256]
    const float* __restrict__ bo,          // [128]
    const float* __restrict__ h_old,       // h(t-2)
    float* __restrict__ h_new,             // h(t-1) (out; zeros when t==0)
    const float* __restrict__ sv_in, float* __restrict__ sv_out,
    const float* __restrict__ ov_in, float* __restrict__ ov_out,
    const float* __restrict__ att_in,      // att(t-1)
    float* __restrict__ att_out,           // att(t)
    float* __restrict__ outs_prev,         // outs[t-1]
    int* __restrict__ cnt1, int* __restrict__ cnt2, int t, int do_B)
{
    __shared__ float p_s[1024 * 10];       // [key][8 rows + 2 pad]
    __shared__ float v_s[64 * 36];         // [key-in-chunk][32 d + 4 pad]
    __shared__ float hA_s[8 * 128];
    __shared__ float h2_s[8 * 128];
    __shared__ float att_s[8 * 128];
    __shared__ float q_s[8 * 36];
    __shared__ float red_s[8 * 33];
    __shared__ float mrow_s[8], linv_s[8], thr_s[2];

    const int tid = threadIdx.x;
    const int hh = blockIdx.x >> 7;
    const int r0 = (blockIdx.x & 127) * 8;
    const bool wr = (hh == 0);

    if (t > 0) {
        // ---- A0: thresholds (exact integer recursion) + loads ----
        if (tid == 0) {
            float ts = 1.0f, to = 1.0f;
            for (int i = 0; i < t - 1; ++i) {
                float e1 = (float)cnt1[i] * (1.f / 131072.f) - 0.02f;
                ts = fmaxf(ts + 0.1f * e1, 0.5f);
                float e2 = (float)cnt2[i] * (1.f / 262144.f) - 0.02f;
                to = fmaxf(to + 0.1f * e2, 0.5f);
            }
            thr_s[0] = ts; thr_s[1] = to;
        }
#pragma unroll
        for (int i = 0; i < 4; ++i) {
            int idx = i * 256 + tid;
            hA_s[idx]  = h_old[r0 * 128 + idx];
            att_s[idx] = att_in[r0 * 128 + idx];
        }
        __syncthreads();

        // ---- A1: st = h_old@W1T[:,:128], b = att@WoT; upd -> LIF1 -> h2 ----
        {
            const int n = tid & 127, half = tid >> 7;
            float st[4] = {0.f, 0.f, 0.f, 0.f};
            float b[4]  = {0.f, 0.f, 0.f, 0.f};
            for (int k4 = 0; k4 < 32; ++k4) {
                const int k = k4 * 4;
                float w10 = W1T[(k + 0) * 256 + n];
                float w11 = W1T[(k + 1) * 256 + n];
                float w12 = W1T[(k + 2) * 256 + n];
                float w13 = W1T[(k + 3) * 256 + n];
                float wo0 = WoT[(k + 0) * 128 + n];
                float wo1 = WoT[(k + 1) * 128 + n];
                float wo2 = WoT[(k + 2) * 128 + n];
                float wo3 = WoT[(k + 3) * 128 + n];
#pragma unroll
                for (int r4 = 0; r4 < 4; ++r4) {
                    int r = half * 4 + r4;
                    float4 hv = *(const float4*)&hA_s[r * 128 + k];
                    float4 av = *(const float4*)&att_s[r * 128 + k];
                    st[r4] += hv.x * w10; st[r4] += hv.y * w11;
                    st[r4] += hv.z * w12; st[r4] += hv.w * w13;
                    b[r4] += av.x * wo0; b[r4] += av.y * wo1;
                    b[r4] += av.z * wo2; b[r4] += av.w * wo3;
                }
            }
            float ts = thr_s[0];
            int my1 = 0;
#pragma unroll
            for (int r4 = 0; r4 < 4; ++r4) {
                int r = half * 4 + r4, row = r0 + r;
                float x = b[r4] + bo[n];
                x += st[r4];
                float v = sv_in[row * 128 + n];
                float vp = v * DECAYF + x;
                float sp = (vp - ts >= 0.f) ? 1.f : 0.f;
                h2_s[r * 128 + n] = sp;
                if (wr) {
                    h_new[row * 128 + n]  = sp;
                    sv_out[row * 128 + n] = vp * (1.f - sp);
                }
                my1 += (int)sp;
            }
            if (wr) {
#pragma unroll
                for (int off = 32; off > 0; off >>= 1) my1 += __shfl_down(my1, off, 64);
                if ((tid & 63) == 0) atomicAdd(&cnt1[t - 1], my1);
            }
        }
        __syncthreads();

        // ---- A2: out_pot = h2@CT -> LIF2 -> outs[t-1] (writer blocks only) ----
        if (wr) {
            const int n = tid;
            float acc[8] = {0.f, 0.f, 0.f, 0.f, 0.f, 0.f, 0.f, 0.f};
            for (int k4 = 0; k4 < 32; ++k4) {
                const int k = k4 * 4;
                float c0 = CT[(k + 0) * 256 + n];
                float c1 = CT[(k + 1) * 256 + n];
                float c2 = CT[(k + 2) * 256 + n];
                float c3 = CT[(k + 3) * 256 + n];
#pragma unroll
                for (int r = 0; r < 8; ++r) {
                    float4 hv = *(const float4*)&h2_s[r * 128 + k];
                    acc[r] += hv.x * c0; acc[r] += hv.y * c1;
                    acc[r] += hv.z * c2; acc[r] += hv.w * c3;
                }
            }
            float to = thr_s[1];
            int my2 = 0;
#pragma unroll
            for (int r = 0; r < 8; ++r) {
                int row = r0 + r;
                float vo = ov_in[row * 256 + n];
                float vp = vo * DECAYF + acc[r];
                float sp = (vp - to >= 0.f) ? 1.f : 0.f;
                outs_prev[(size_t)row * 256 + n] = sp;
                ov_out[row * 256 + n] = vp * (1.f - sp);
                my2 += (int)sp;
            }
#pragma unroll
            for (int off = 32; off > 0; off >>= 1) my2 += __shfl_down(my2, off, 64);
            if ((tid & 63) == 0) atomicAdd(&cnt2[t - 1], my2);
        }
    } else {
        // t == 0: h(t-1) = zeros (h_new buffer zero-initialized by init_k)
#pragma unroll
        for (int i = 0; i < 4; ++i) {
            int idx = i * 256 + tid;
            h2_s[idx] = h_new[r0 * 128 + idx];
        }
        __syncthreads();
    }

    if (!do_B) return;

    // ---- B1: q[r][d] for this head (ascending-k fma, matches reference) ----
    {
        const int r = tid >> 5, d = tid & 31;
        const int col = 128 + hh * 32 + d;
        float acc = 0.f;
        for (int k4 = 0; k4 < 32; ++k4) {
            const int k = k4 * 4;
            float4 hv = *(const float4*)&h2_s[r * 128 + k];
            float w0 = W1T[(k + 0) * 256 + col];
            float w1 = W1T[(k + 1) * 256 + col];
            float w2 = W1T[(k + 2) * 256 + col];
            float w3 = W1T[(k + 3) * 256 + col];
            acc += hv.x * w0; acc += hv.y * w1; acc += hv.z * w2; acc += hv.w * w3;
        }
        q_s[r * 36 + d] = acc + B1[col];
    }
    __syncthreads();

    // ---- B2: scores. Wave w owns rows {2w,2w+1}; q held in registers. ----
    {
        const int w = tid >> 6, lane = tid & 63;
        float4 qr0[8], qr1[8];
#pragma unroll
        for (int d4 = 0; d4 < 8; ++d4) {
            qr0[d4] = *(const float4*)&q_s[(2 * w) * 36 + d4 * 4];
            qr1[d4] = *(const float4*)&q_s[(2 * w + 1) * 36 + d4 * 4];
        }
        const float* kTh = kT + hh * 32 * 1024;
        for (int kk = 0; kk < 16; ++kk) {
            const int key = kk * 64 + lane;
            float kreg[32];
#pragma unroll
            for (int d = 0; d < 32; ++d) kreg[d] = kTh[d * 1024 + key];
            float a0 = 0.f, a1 = 0.f;
#pragma unroll
            for (int d4 = 0; d4 < 8; ++d4) {
                a0 += qr0[d4].x * kreg[d4 * 4 + 0]; a0 += qr0[d4].y * kreg[d4 * 4 + 1];
                a0 += qr0[d4].z * kreg[d4 * 4 + 2]; a0 += qr0[d4].w * kreg[d4 * 4 + 3];
                a1 += qr1[d4].x * kreg[d4 * 4 + 0]; a1 += qr1[d4].y * kreg[d4 * 4 + 1];
                a1 += qr1[d4].z * kreg[d4 * 4 + 2]; a1 += qr1[d4].w * kreg[d4 * 4 + 3];
            }
            *(float2*)&p_s[key * 10 + 2 * w] = make_float2(a0 * SCALEF, a1 * SCALEF);
        }
    }
    __syncthreads();

    // ---- B3: softmax (identical per-row reduction order to rounds 1-3) ----
    {
        const int rh = tid >> 5, lg = tid & 31;
        float mx = -1e30f;
        for (int jj = 0; jj < 32; ++jj)
            mx = fmaxf(mx, p_s[(lg + 32 * jj) * 10 + rh]);
        red_s[rh * 33 + lg] = mx;
        __syncthreads();
        if (tid < 8) {
            float m = red_s[tid * 33];
            for (int j = 1; j < 32; ++j) m = fmaxf(m, red_s[tid * 33 + j]);
            mrow_s[tid] = m;
        }
        __syncthreads();
        float m = mrow_s[rh];
        float ls = 0.f;
        for (int jj = 0; jj < 32; ++jj) {
            int a = (lg + 32 * jj) * 10 + rh;
            float p = expf(p_s[a] - m);
            p_s[a] = p;
            ls += p;
        }
        red_s[rh * 33 + lg] = ls;
        __syncthreads();
        if (tid < 8) {
            float l = 0.f;
            for (int j = 0; j < 32; ++j) l += red_s[tid * 33 + j];
            linv_s[tid] = 1.0f / l;
        }
    }
    __syncthreads();

    // ---- B4: PV outer-product from LDS. Thread tile 2 rows x 2 dims. ----
    {
        const int pr = tid & 3;            // row-pair: rows 2pr, 2pr+1
        const int pd = (tid >> 2) & 15;    // dim-pair: dims 2pd, 2pd+1
        const bool act = (tid < 64);
        const float4* kv4 = (const float4*)kv;
        float a00 = 0.f, a01 = 0.f, a10 = 0.f, a11 = 0.f;
        for (int c = 0; c < 16; ++c) {
            __syncthreads();               // v_s safe to overwrite
#pragma unroll
            for (int i = 0; i < 2; ++i) {
                int idx = i * 256 + tid;
                int key = idx >> 3, dq = idx & 7;
                *(float4*)&v_s[key * 36 + dq * 4] =
                    kv4[(size_t)(c * 64 + key) * 64 + 32 + hh * 8 + dq];
            }
            __syncthreads();
            if (act) {
#pragma unroll 8
                for (int j = 0; j < 64; ++j) {
                    int key = c * 64 + j;
                    float2 p2 = *(const float2*)&p_s[key * 10 + pr * 2];
                    float2 v2 = *(const float2*)&v_s[j * 36 + pd * 2];
                    a00 += p2.x * v2.x; a01 += p2.x * v2.y;
                    a10 += p2.y * v2.x; a11 += p2.y * v2.y;
                }
            }
        }
        if (act) {
            float li0 = linv_s[2 * pr], li1 = linv_s[2 * pr + 1];
            *(float2*)&att_out[(r0 + 2 * pr) * 128 + hh * 32 + 2 * pd] =
                make_float2(a00 * li0, a01 * li0);
            *(float2*)&att_out[(r0 + 2 * pr + 1) * 128 + hh * 32 + 2 * pd] =
                make_float2(a10 * li1, a11 * li1);
        }
    }
}

// ======================= host =======================
extern "C" void kernel_launch(void* const* d_in, const int* in_sizes, int n_in,
                              void* d_out, int out_size, void* d_ws, size_t ws_size,
                              hipStream_t stream) {
    (void)in_sizes; (void)n_in; (void)out_size; (void)ws_size;
    const int*   ids  = (const int*)d_in[0];
    const float* emb  = (const float*)d_in[1];
    const float* Aw   = (const float*)d_in[2];
    const float* Cw   = (const float*)d_in[3];
    const float* Wq   = (const float*)d_in[4];
    const float* bq   = (const float*)d_in[5];
    const float* Wkv  = (const float*)d_in[6];
    const float* bkv  = (const float*)d_in[7];
    const float* Wo   = (const float*)d_in[8];
    const float* bo   = (const float*)d_in[9];
    const float* Wout = (const float*)d_in[10];
    const float* bout = (const float*)d_in[11];
    float* out = (float*)d_out;
    float* ws  = (float*)d_ws;

    float* tok  = ws;                       // 262144
    float* bufA = tok  + NE;                // 8*262144
    float* bufB = bufA + 8 * NE;            // 8*262144
    float* kvb  = bufB + 8 * NE;            // 8*262144
    float* kTb  = kvb  + 8 * NE;            // 8*131072
    float* attb0 = kTb  + 8 * 131072;       // 131072
    float* attb1 = attb0 + 131072;          // 131072
    float* hb0  = attb1 + 131072;           // 131072
    float* hb1  = hb0  + 131072;            // 131072
    float* svb0 = hb1  + 131072;            // 131072
    float* svb1 = svb0 + 131072;            // 131072
    float* ovb0 = svb1 + 131072;            // 262144
    float* ovb1 = ovb0 + 262144;            // 262144
    float* ti   = ovb1 + 262144;            // 262144
    float* W1T  = ti   + NE;                // 32768
    float* B1   = W1T  + 32768;             // 256
    float* WoT  = B1   + 256;               // 16384
    float* CT   = WoT  + 16384;             // 32768
    int*   cnts = (int*)(CT + 32768);       // cnt1[8], cnt2[8]

    float* hb[2]   = {hb0, hb1};
    float* svb[2]  = {svb0, svb1};
    float* ovb[2]  = {ovb0, ovb1};
    float* attb[2] = {attb0, attb1};

    embed_k<<<dim3(1024), dim3(256), 0, stream>>>(ids, emb, tok);

    for (int l = 0; l < 2; ++l) {
        const float* Al   = Aw  + l * 16384;
        const float* Cl   = Cw  + l * 32768;
        const float* Wql  = Wq  + l * 16384;
        const float* bql  = bq  + l * 128;
        const float* Wkvl = Wkv + l * 65536;
        const float* bkvl = bkv + l * 256;
        const float* Wol  = Wo  + l * 16384;
        const float* bol  = bo  + l * 128;
        const float* xin  = (l == 0) ? tok : bufA;
        float* outs       = (l == 0) ? bufA : bufB;
        const int Mkv     = (l == 0) ? BS_TOT : 8 * BS_TOT;
        const int nt      = (l == 0) ? 1 : 8;

        init_k<<<dim3(1024), dim3(256), 0, stream>>>(hb0, hb1, svb0, svb1, ovb0, ovb1,
                                                     W1T, B1, WoT, CT,
                                                     Al, Wql, bql, Wol, Cl, cnts);

        gemm_k<64, 64, 16, 4, 4><<<dim3(256 / 64, Mkv / 64), dim3(256), 0, stream>>>(
            xin, Wkvl, bkvl, kvb, Mkv, 256, 256);

        ktrans_k<<<dim3(16, nt), dim3(256), 0, stream>>>(kvb, kTb);

        for (int t = 0; t <= TSTEPS; ++t) {
            const int do_B = (t < TSTEPS) ? 1 : 0;
            const int tt = (t < TSTEPS) ? t : (TSTEPS - 1);
            const float* kT_t = (l == 0) ? kTb : kTb + (size_t)tt * 131072;
            const float* kv_t = (l == 0) ? kvb : kvb + (size_t)tt * NE;
            float* outs_prev = outs + (size_t)((t > 0) ? (t - 1) : 0) * NE;
            const int grid = do_B ? 512 : 128;
            fstep_k<<<dim3(grid), dim3(256), 0, stream>>>(
                kT_t, kv_t, W1T, B1, WoT, CT, bol,
                hb[t & 1], hb[(t + 1) & 1],
                svb[t & 1], svb[(t + 1) & 1],
                ovb[t & 1], ovb[(t + 1) & 1],
                attb[(t + 1) & 1], attb[t & 1],
                outs_prev, cnts, cnts + 8, t, do_B);
        }
    }

    mean_k<<<dim3(1024), dim3(256), 0, stream>>>(bufB, ti);

    // logits = ti @ Wout^T + bout.  256x32 tile: Wout read 4x (was 16x).
    gemm_k<256, 32, 16, 8, 4><<<dim3(32000 / 32, BS_TOT / 256), dim3(256), 0, stream>>>(
        ti, Wout, bout, out, BS_TOT, 32000, 256);
}